// Round 10
// baseline (408.515 us; speedup 1.0000x reference)
//
#include <hip/hip_runtime.h>

#define HH 192
#define WW 192
#define HWPIX (HH * WW)
#define PLANE 5184           // 324 px * 16 B per c-octet plane
#define CHUNKB 20736         // 4 planes per 32c chunk

typedef __attribute__((ext_vector_type(8))) short bf16x8;
typedef __attribute__((ext_vector_type(4))) float f32x4;
typedef __attribute__((ext_vector_type(4))) unsigned int u32x4;

__device__ __forceinline__ unsigned f2bf(float f) {
    unsigned u = __builtin_bit_cast(unsigned, f);
    return (u + 0x7FFFu + ((u >> 16) & 1u)) >> 16;
}

__device__ __forceinline__ unsigned cvtpk(float lo, float hi) {
    unsigned r;
    asm("v_cvt_pk_bf16_f32 %0, %1, %2" : "=v"(r) : "v"(lo), "v"(hi));
    return r;
}

// ---------------- weight fusion (r9 layout, proven) ----------------
// frag = ((cc*3 + kw)*3 + kh)*8 + ot ; within frag: ln*8 + j  (shorts)
// ot=o>>4, ln=((c>>3)&3)*16+(o&15), j=c&7, cc=c>>5
__global__ void fuse_weights(const float* __restrict__ wsq, const float* __restrict__ wv,
                             const float* __restrict__ whr, const float* __restrict__ w19,
                             const float* __restrict__ w37, unsigned short* __restrict__ wbuf) {
    int idx = blockIdx.x * 256 + threadIdx.x;
    if (idx >= 128 * 128 * 9) return;
    int o = idx / 1152;
    int r = idx - o * 1152;
    int c = r / 9;
    int tap = r - c * 9;
    int kh = tap / 3, kw = tap - kh * 3;
    float v = wsq[((o * 128 + c) * 3 + kh) * 3 + kw];
    if (kw == 1) v += wv[(o * 128 + c) * 3 + kh];
    if (kh == 1) v += whr[(o * 128 + c) * 3 + kw];
    if (kh == kw) v += w19[((o * 128 + c) * 3 + kh) * 3 + kw];
    if (kh + kw == 2) v += w37[((o * 128 + c) * 3 + kh) * 3 + kw];
    int cc = c >> 5, ot = o >> 4;
    int ln = ((c >> 3) & 3) * 16 + (o & 15);
    int j = c & 7;
    int frag = ((cc * 3 + kw) * 3 + kh) * 8 + ot;
    wbuf[(size_t)frag * 512 + ln * 8 + j] = (unsigned short)f2bf(v);
}

// ---------------- single-pass conv, 8 waves, high occupancy ----------------
// Block: 512 thr = 8 waves = (oq: o-quarter 0..3) x (ni: row-half 0..1).
// Per wave: 32 o x 8 rows x 16 px -> acc = 2x8 f32x4 = 64 regs/lane.
// Staging: 1296 lane-tasks (4 c-octets x 324 px), 3 rounds; task = 8 coalesced
// dword loads -> cvt_pk -> one ds_write_b128 into [slot][px][16B] (r7-proven).
// Compute: kw-outer, rr-outer (10 ds_read_b128/pass), B-frag reused by 3 kh.
__global__ __launch_bounds__(512, 4) void conv8(const float* __restrict__ x,
                                                const unsigned short* __restrict__ wbuf,
                                                float* __restrict__ out) {
    __shared__ __align__(1024) unsigned char lds[2 * CHUNKB];
    const int t = threadIdx.x, l = t & 63, wvid = t >> 6;
    const int oq = wvid >> 1, ni = wvid & 1;
    const int l15 = l & 15, l4 = l >> 4;

    // XCD-chunked bijective swizzle: 2304 = 8 x 288 (= 2 full batches/XCD).
    int id = (int)blockIdx.x;
    int id2 = (id & 7) * 288 + (id >> 3);
    int b = id2 / 144;
    int rem = id2 - b * 144;
    int by = rem / 12, bx = rem - by * 12;
    const int h0 = by * 16, w0 = bx * 16;

    const float* __restrict__ xb = x + (size_t)b * (128 * HWPIX);

    f32x4 acc[2][8];
    const f32x4 zero = {0.f, 0.f, 0.f, 0.f};
#pragma unroll
    for (int m = 0; m < 2; ++m)
#pragma unroll
        for (int np = 0; np < 8; ++np) acc[m][np] = zero;

    float svA[8], svB[8];

    // task idx = t + 512*R < 1296: slot = idx/324 (c-octet), px = idx%324
#define LOADR(CC, R, SV)                                                                 \
    {                                                                                    \
        int idx_ = t + 512 * (R);                                                        \
        if ((R) < 2 || idx_ < 1296) {                                                    \
            int slot_ = idx_ / 324;                                                      \
            int px_ = idx_ - slot_ * 324;                                                \
            int ih_ = px_ / 18, iw_ = px_ - ih_ * 18;                                    \
            int gh_ = h0 - 1 + ih_, gw_ = w0 - 1 + iw_;                                  \
            int ghc_ = min(max(gh_, 0), HH - 1);                                         \
            int gwc_ = min(max(gw_, 0), WW - 1);                                         \
            const float* p_ =                                                            \
                xb + (size_t)((CC) * 32 + slot_ * 8) * HWPIX + ghc_ * WW + gwc_;         \
            _Pragma("unroll") for (int j = 0; j < 8; ++j) SV[j] = p_[(size_t)j * HWPIX]; \
        }                                                                                \
    }

#define WRITER(R, BB, SV)                                                                \
    {                                                                                    \
        int idx_ = t + 512 * (R);                                                        \
        if ((R) < 2 || idx_ < 1296) {                                                    \
            int slot_ = idx_ / 324;                                                      \
            int px_ = idx_ - slot_ * 324;                                                \
            int ih_ = px_ / 18, iw_ = px_ - ih_ * 18;                                    \
            int gh_ = h0 - 1 + ih_, gw_ = w0 - 1 + iw_;                                  \
            int ok_ = ((unsigned)gh_ < (unsigned)HH) & ((unsigned)gw_ < (unsigned)WW);   \
            u32x4 pk;                                                                    \
            _Pragma("unroll") for (int q = 0; q < 4; ++q) {                              \
                unsigned v_ = cvtpk(SV[2 * q], SV[2 * q + 1]);                           \
                pk[q] = ok_ ? v_ : 0u;                                                   \
            }                                                                            \
            *(u32x4*)(lds + (BB) + slot_ * PLANE + px_ * 16) = pk;                       \
        }                                                                                \
    }

#define KWPASS(KW)                                                                       \
    {                                                                                    \
        const unsigned short* wp =                                                       \
            wbuf + ((size_t)(((cc * 3 + (KW)) * 3) * 8 + oq * 2)) * 512 + l * 8;         \
        bf16x8 a[6];                                                                     \
        _Pragma("unroll") for (int kh = 0; kh < 3; ++kh)                                 \
            _Pragma("unroll") for (int m = 0; m < 2; ++m)                                \
                a[kh * 2 + m] = *(const bf16x8*)(wp + (kh * 8 + m) * 512);               \
        __builtin_amdgcn_s_setprio(1);                                                   \
        _Pragma("unroll") for (int rr = 0; rr < 10; ++rr) {                              \
            int px_ = (ni * 8 + rr) * 18 + (KW) + l15;                                   \
            bf16x8 bf = *(const bf16x8*)(lds + bb + l4 * PLANE + px_ * 16);              \
            _Pragma("unroll") for (int kh = 0; kh < 3; ++kh) {                           \
                const int np = rr - kh;                                                  \
                if (np >= 0 && np < 8) {                                                 \
                    _Pragma("unroll") for (int m = 0; m < 2; ++m)                        \
                        acc[m][np] = __builtin_amdgcn_mfma_f32_16x16x32_bf16(            \
                            a[kh * 2 + m], bf, acc[m][np], 0, 0, 0);                     \
                }                                                                        \
            }                                                                            \
        }                                                                                \
        __builtin_amdgcn_s_setprio(0);                                                   \
    }

    // prologue: stage chunk 0 into buffer 0
    LOADR(0, 0, svA)
    WRITER(0, 0, svA)
    LOADR(0, 1, svA)
    WRITER(1, 0, svA)
    LOADR(0, 2, svA)
    WRITER(2, 0, svA)
    __syncthreads();

    int bb = 0;
#pragma unroll 1
    for (int cc = 0; cc < 4; ++cc) {
        if (cc < 3) { LOADR(cc + 1, 0, svA) }
        KWPASS(0)
        if (cc < 3) {
            WRITER(0, bb ^ CHUNKB, svA)
            LOADR(cc + 1, 1, svB)
        }
        KWPASS(1)
        if (cc < 3) {
            WRITER(1, bb ^ CHUNKB, svB)
            LOADR(cc + 1, 2, svA)
        }
        KWPASS(2)
        if (cc < 3) { WRITER(2, bb ^ CHUNKB, svA) }
        __syncthreads();
        bb ^= CHUNKB;
    }

    // epilogue: D row=(l>>4)*4+j -> o, col=l&15 -> w; wave rows = ni*8+np
    float* __restrict__ ob =
        out + (size_t)b * (128 * HWPIX) + (size_t)(h0 + ni * 8) * WW + w0 + l15;
#pragma unroll
    for (int m = 0; m < 2; ++m) {
#pragma unroll
        for (int j = 0; j < 4; ++j) {
            int o = oq * 32 + m * 16 + l4 * 4 + j;
            float* op = ob + (size_t)o * HWPIX;
#pragma unroll
            for (int np = 0; np < 8; ++np)
                op[np * WW] = acc[m][np][j];
        }
    }
}

extern "C" void kernel_launch(void* const* d_in, const int* in_sizes, int n_in,
                              void* d_out, int out_size, void* d_ws, size_t ws_size,
                              hipStream_t stream) {
    const float* x   = (const float*)d_in[0];
    const float* wsq = (const float*)d_in[1];
    const float* wvv = (const float*)d_in[2];
    const float* wh  = (const float*)d_in[3];
    const float* w19 = (const float*)d_in[4];
    const float* w37 = (const float*)d_in[5];

    unsigned short* wbuf = (unsigned short*)d_ws;  // 294,912 B

    fuse_weights<<<576, 256, 0, stream>>>(wsq, wvv, wh, w19, w37, wbuf);
    conv8<<<2304, 512, 0, stream>>>(x, wbuf, (float*)d_out);
}